// Round 8
// baseline (255.116 us; speedup 1.0000x reference)
//
#include <hip/hip_runtime.h>
#include <math.h>

// NT-Xent (SimCLR) loss. B=4096, D=256, T=0.5.  SINGLE fused kernel.
// zb = bf16( SCALE * normalize(concat(emb_i, emb_j)) ), SCALE = sqrt(2*log2 e)
//   => acc = zb@zb^T = 2*log2(e)*sim, exp(2*sim) == exp2(acc).
// Phase 1: first 512 entry-tickets normalize 16 rows each (512 <= guaranteed
//   resident blocks ~1024 at 32KB LDS -> deadlock-free), release normDone;
//   everyone acquire-spins to 512.
// Phase 2: 2080 upper-triangle 128x128 tiles (R3 structure: 256 thr, BK=64,
//   fragment-ordered LDS -> conflict-free ds_read_b128, global_load_lds w=16,
//   specialized diag/off-diag epilogues). Row/col sums -> device atomicAdd
//   into dsum[8192]. pos tiles (by==bx+32): shuffle-reduce -> atomicAdd(posSum).
// Phase 3: release done-ticket; last 32 tickets acquire-spin to 2080, then
//   each -log()s a 256-row slice of dsum into out[0].
// loss = (1/8192) * ( (2*ln2)*posSum - sum_r log(dsum[r]) )

#define NROWS 8192
#define NHALF 4096
#define DIM   256
#define BM    128
#define NCB   64                    // 128-row blocks
#define NTRI  (NCB * (NCB + 1) / 2) // 2080 triangle tiles
#define NWORK 512                   // normalize worker blocks (16 rows each)
#define NRED  32                    // reducer blocks (256 rows each)

#define SCALE    1.69864344f   // sqrt(2*log2(e))
#define POSMUL   1.38629436f   // 4 / (2*log2(e)) = 2*ln2

typedef __attribute__((ext_vector_type(8))) short bf16x8;
typedef __attribute__((ext_vector_type(8))) unsigned short u16x8;
typedef __attribute__((ext_vector_type(4))) float f32x4;

#if __has_builtin(__builtin_amdgcn_exp2f)
#define EXP2(x) __builtin_amdgcn_exp2f(x)
#else
#define EXP2(x) __expf((x) * 0.69314718f)
#endif

static __device__ __forceinline__ unsigned short f2bf(float x) {
  unsigned int u = __float_as_uint(x);
  unsigned int r = (u + 0x7FFFu + ((u >> 16) & 1u)) >> 16;
  return (unsigned short)r;
}

__global__ __launch_bounds__(256) void fused_kernel(
    const float* __restrict__ emb_i, const float* __restrict__ emb_j,
    unsigned short* __restrict__ zb, float* __restrict__ dsum,
    float* __restrict__ posSum, int* __restrict__ workCnt,
    int* __restrict__ normDone, int* __restrict__ doneCnt,
    float* __restrict__ out) {
  // 16 fragment regions x 1024 B per operand (32 KB total).
  __shared__ __attribute__((aligned(16))) unsigned short As[16 * 512];
  __shared__ __attribute__((aligned(16))) unsigned short Bs[16 * 512];
  int* ish = (int*)As;
  float* red = (float*)As;

  const int tid = threadIdx.x;
  const int w = tid >> 6;
  const int lane = tid & 63;
  const int wr = w >> 1, wc = w & 1;  // 2x2 wave grid, 64x64 each
  const int quad = lane >> 4;
  const int m16 = lane & 15;

  // ---- entry ticket ----
  if (tid == 0)
    ish[0] = __hip_atomic_fetch_add(workCnt, 1, __ATOMIC_RELAXED,
                                    __HIP_MEMORY_SCOPE_AGENT);
  __syncthreads();
  const int t0 = ish[0];
  __syncthreads();

  // ---- phase 1: normalize (first NWORK tickets, 16 rows each) ----
  if (t0 < NWORK) {
    int row = t0 * 16 + (tid >> 4);
    int sub = tid & 15;  // 16 elems per thread
    const float* src = (row < NHALF) ? emb_i + (size_t)row * DIM
                                     : emb_j + (size_t)(row - NHALF) * DIM;
    float4 v0 = ((const float4*)src)[sub * 4 + 0];
    float4 v1 = ((const float4*)src)[sub * 4 + 1];
    float4 v2 = ((const float4*)src)[sub * 4 + 2];
    float4 v3 = ((const float4*)src)[sub * 4 + 3];
    float ss = v0.x * v0.x + v0.y * v0.y + v0.z * v0.z + v0.w * v0.w +
               v1.x * v1.x + v1.y * v1.y + v1.z * v1.z + v1.w * v1.w +
               v2.x * v2.x + v2.y * v2.y + v2.z * v2.z + v2.w * v2.w +
               v3.x * v3.x + v3.y * v3.y + v3.z * v3.z + v3.w * v3.w;
    #pragma unroll
    for (int off = 1; off < 16; off <<= 1) ss += __shfl_xor(ss, off, 16);
    float inv = SCALE / fmaxf(sqrtf(ss), 1e-12f);
    u16x8 o0, o1;
    o0[0] = f2bf(v0.x * inv); o0[1] = f2bf(v0.y * inv);
    o0[2] = f2bf(v0.z * inv); o0[3] = f2bf(v0.w * inv);
    o0[4] = f2bf(v1.x * inv); o0[5] = f2bf(v1.y * inv);
    o0[6] = f2bf(v1.z * inv); o0[7] = f2bf(v1.w * inv);
    o1[0] = f2bf(v2.x * inv); o1[1] = f2bf(v2.y * inv);
    o1[2] = f2bf(v2.z * inv); o1[3] = f2bf(v2.w * inv);
    o1[4] = f2bf(v3.x * inv); o1[5] = f2bf(v3.y * inv);
    o1[6] = f2bf(v3.z * inv); o1[7] = f2bf(v3.w * inv);
    u16x8* dst = (u16x8*)&zb[(size_t)row * DIM + sub * 16];
    dst[0] = o0; dst[1] = o1;
    __syncthreads();  // drains vmcnt before barrier: all block stores issued
    if (tid == 0)
      __hip_atomic_fetch_add(normDone, 1, __ATOMIC_RELEASE,
                             __HIP_MEMORY_SCOPE_AGENT);
  }

  // ---- wait for all rows ----
  if (tid == 0) {
    while (__hip_atomic_load(normDone, __ATOMIC_ACQUIRE,
                             __HIP_MEMORY_SCOPE_AGENT) < NWORK)
      __builtin_amdgcn_s_sleep(8);
  }
  __syncthreads();

  // ---- phase 2: triangle tile decode ----
  int t = blockIdx.x;
  int by = (int)((sqrtf(8.0f * (float)t + 1.0f) - 1.0f) * 0.5f);
  while ((by + 1) * (by + 2) / 2 <= t) ++by;
  while (by * (by + 1) / 2 > t) --by;
  int bx = t - by * (by + 1) / 2;
  const int row0 = bx * BM;
  const int col0 = by * BM;

  f32x4 acc[4][4];
  #pragma unroll
  for (int i = 0; i < 4; ++i)
    #pragma unroll
    for (int j = 0; j < 4; ++j) {
      f32x4 z4 = {0.f, 0.f, 0.f, 0.f};
      acc[i][j] = z4;
    }

  // Region ra (0..15): row-group g=ra>>1 (rows g*16+m16), k-half c=ra&1
  // (k = c*32 + quad*8). Wave w stages ra = w*4+t4 per operand.
  for (int kc = 0; kc < DIM; kc += 64) {
    #pragma unroll
    for (int t4 = 0; t4 < 4; ++t4) {
      int ra = w * 4 + t4;
      int grow = (ra >> 1) * 16 + m16;
      int gk = kc + (ra & 1) * 32 + quad * 8;
      __builtin_amdgcn_global_load_lds(
          (const __attribute__((address_space(1))) unsigned int*)
              &zb[(size_t)(row0 + grow) * DIM + gk],
          (__attribute__((address_space(3))) unsigned int*)&As[ra * 512],
          16, 0, 0);
      __builtin_amdgcn_global_load_lds(
          (const __attribute__((address_space(1))) unsigned int*)
              &zb[(size_t)(col0 + grow) * DIM + gk],
          (__attribute__((address_space(3))) unsigned int*)&Bs[ra * 512],
          16, 0, 0);
    }
    __syncthreads();

    #pragma unroll
    for (int kst = 0; kst < 2; ++kst) {
      bf16x8 af[4], bfr[4];
      #pragma unroll
      for (int i = 0; i < 4; ++i)
        af[i] = *(const bf16x8*)&As[(wr * 8 + i * 2 + kst) * 512 + lane * 8];
      #pragma unroll
      for (int j = 0; j < 4; ++j)
        bfr[j] = *(const bf16x8*)&Bs[(wc * 8 + j * 2 + kst) * 512 + lane * 8];
      #pragma unroll
      for (int i = 0; i < 4; ++i)
        #pragma unroll
        for (int j = 0; j < 4; ++j)
          acc[i][j] = __builtin_amdgcn_mfma_f32_16x16x32_bf16(
              af[i], bfr[j], acc[i][j], 0, 0, 0);
    }
    __syncthreads();
  }

  // pos tiles: col0 - row0 == NHALF; local col == local row picks pairs.
  if (col0 - row0 == NHALF) {
    float p = 0.f;
    #pragma unroll
    for (int i = 0; i < 4; ++i)
      #pragma unroll
      for (int j = 0; j < 4; ++j) {
        int lc = wc * 64 + j * 16 + m16;
        #pragma unroll
        for (int r = 0; r < 4; ++r) {
          int lr = wr * 64 + i * 16 + quad * 4 + r;
          if (lc == lr) p += acc[i][j][r];
        }
      }
    #pragma unroll
    for (int off = 32; off; off >>= 1) p += __shfl_down(p, off, 64);
    if (lane == 0) atomicAdd(posSum, p);
  }

  // ---- specialized epilogues (R3 style) ----
  // C layout: local col = wc*64+j*16+m16, local row = wr*64+i*16+quad*4+r.
  if (bx != by) {
    float rs[4][4];
    float cs[4] = {0.f, 0.f, 0.f, 0.f};
    #pragma unroll
    for (int i = 0; i < 4; ++i)
      #pragma unroll
      for (int r = 0; r < 4; ++r) rs[i][r] = 0.f;
    #pragma unroll
    for (int i = 0; i < 4; ++i)
      #pragma unroll
      for (int j = 0; j < 4; ++j)
        #pragma unroll
        for (int r = 0; r < 4; ++r) {
          float e = EXP2(acc[i][j][r]);
          rs[i][r] += e;
          cs[j] += e;
        }
    #pragma unroll
    for (int i = 0; i < 4; ++i)
      #pragma unroll
      for (int r = 0; r < 4; ++r) {
        float v = rs[i][r];
        v += __shfl_xor(v, 1, 16);
        v += __shfl_xor(v, 2, 16);
        v += __shfl_xor(v, 4, 16);
        v += __shfl_xor(v, 8, 16);
        if (m16 == 0) red[wc * 128 + wr * 64 + i * 16 + quad * 4 + r] = v;
      }
    #pragma unroll
    for (int j = 0; j < 4; ++j) {
      float v = cs[j];
      v += __shfl_xor(v, 16, 64);
      v += __shfl_xor(v, 32, 64);
      if (quad == 0) red[256 + wr * 128 + wc * 64 + j * 16 + m16] = v;
    }
    __syncthreads();
    if (tid < 128) {
      atomicAdd(&dsum[row0 + tid], red[tid] + red[128 + tid]);
    } else {
      int c = tid - 128;
      atomicAdd(&dsum[col0 + c], red[256 + c] + red[384 + c]);
    }
  } else {
    float rs[4][4];
    #pragma unroll
    for (int i = 0; i < 4; ++i)
      #pragma unroll
      for (int r = 0; r < 4; ++r) rs[i][r] = 0.f;
    #pragma unroll
    for (int i = 0; i < 4; ++i)
      #pragma unroll
      for (int j = 0; j < 4; ++j) {
        int lcol = wc * 64 + j * 16 + m16;
        #pragma unroll
        for (int r = 0; r < 4; ++r) {
          int lrow = wr * 64 + i * 16 + quad * 4 + r;
          float e = (lrow == lcol) ? 0.f : EXP2(acc[i][j][r]);
          rs[i][r] += e;
        }
      }
    #pragma unroll
    for (int i = 0; i < 4; ++i)
      #pragma unroll
      for (int r = 0; r < 4; ++r) {
        float v = rs[i][r];
        v += __shfl_xor(v, 1, 16);
        v += __shfl_xor(v, 2, 16);
        v += __shfl_xor(v, 4, 16);
        v += __shfl_xor(v, 8, 16);
        if (m16 == 0) red[wc * 128 + wr * 64 + i * 16 + quad * 4 + r] = v;
      }
    __syncthreads();
    if (tid < 128) atomicAdd(&dsum[row0 + tid], red[tid] + red[128 + tid]);
  }

  // ---- phase 3: done ticket + fused final reduction ----
  __syncthreads();  // red reads complete before ish reuse
  if (tid == 0)
    ish[0] = __hip_atomic_fetch_add(doneCnt, 1, __ATOMIC_RELEASE,
                                    __HIP_MEMORY_SCOPE_AGENT);
  __syncthreads();
  int td = ish[0];
  __syncthreads();
  if (td < NTRI - NRED) return;
  int slice = td - (NTRI - NRED);

  if (tid == 0) {
    while (__hip_atomic_load(doneCnt, __ATOMIC_ACQUIRE,
                             __HIP_MEMORY_SCOPE_AGENT) < NTRI)
      __builtin_amdgcn_s_sleep(8);
  }
  __syncthreads();

  int r = slice * 256 + tid;
  float s = __hip_atomic_load(&dsum[r], __ATOMIC_RELAXED,
                              __HIP_MEMORY_SCOPE_AGENT);
  float v = -logf(s);
  #pragma unroll
  for (int off = 32; off; off >>= 1) v += __shfl_down(v, off, 64);
  if (lane == 0) red[w] = v;
  __syncthreads();
  if (tid == 0) {
    float total = red[0] + red[1] + red[2] + red[3];
    if (slice == 0) {
      float ps = __hip_atomic_load(posSum, __ATOMIC_RELAXED,
                                   __HIP_MEMORY_SCOPE_AGENT);
      total += POSMUL * ps;
    }
    atomicAdd(out, total * (1.0f / 8192.0f));
  }
}

extern "C" void kernel_launch(void* const* d_in, const int* in_sizes, int n_in,
                              void* d_out, int out_size, void* d_ws,
                              size_t ws_size, hipStream_t stream) {
  const float* emb_i = (const float*)d_in[0];
  const float* emb_j = (const float*)d_in[1];
  unsigned short* zb = (unsigned short*)d_ws;         // 4 MB
  float* dsum = (float*)(zb + (size_t)NROWS * DIM);   // 8192 f32
  float* posSum = dsum + NROWS;                       // 1 f32
  int* workCnt = (int*)(posSum + 1);                  // 3 ints
  int* normDone = workCnt + 1;
  int* doneCnt = workCnt + 2;
  float* out = (float*)d_out;

  // zero dsum + posSum + the 3 counters, and the output accumulator
  hipMemsetAsync(dsum, 0, (NROWS + 1) * sizeof(float) + 3 * sizeof(int),
                 stream);
  hipMemsetAsync(out, 0, sizeof(float), stream);
  fused_kernel<<<NTRI, 256, 0, stream>>>(emb_i, emb_j, zb, dsum, posSum,
                                         workCnt, normDone, doneCnt, out);
}

// Round 9
// 161.384 us; speedup vs baseline: 1.5808x; 1.5808x over previous
//
#include <hip/hip_runtime.h>
#include <math.h>

// NT-Xent (SimCLR) loss. B=4096, D=256, T=0.5.
// zb = bf16( SCALE * normalize(concat(emb_i, emb_j)) ), SCALE = sqrt(2*log2 e)
//   => acc = zb@zb^T = 2*log2(e)*sim, exp(2*sim) == exp2(acc).
// LDS-FREE GEMM: each wave loads its MFMA fragments DIRECTLY from global
// (16B/lane, 16 rows x 64B segments/instr, L1-reused by the 2 waves sharing a
// panel). No staging, no barriers, no vmcnt(0) drains -> compiler freely
// interleaves loads with MFMA (R2-R8 showed the LDS/barrier chain, not any
// pipe, was the ~50 us floor). 2x L2 traffic (532 MB ~ 15 us) is affordable.
// Upper-triangle 128x128 tiles (2080 blocks): row/col sums -> device-scope
// atomicAdd into dsum[8192] (coherent point, cross-XCD safe). pos tiles
// (by==bx+32) -> atomicAdd(posSum). Fence-free fused finish (R7-proven):
// barrier-drained atomics + relaxed ticket; last 32 tickets acquire-spin,
// then -log() a 256-row slice into out[0]. 2 launches total.
// loss = (1/8192) * ( (2*ln2)*posSum - sum_r log(dsum[r]) )

#define NROWS 8192
#define NHALF 4096
#define DIM   256
#define BM    128
#define NCB   64                    // 128-row blocks
#define NTRI  (NCB * (NCB + 1) / 2) // 2080 triangle tiles
#define NRED  32                    // reducer blocks (256 rows each)

#define SCALE    1.69864344f   // sqrt(2*log2(e))
#define POSMUL   1.38629436f   // 4 / (2*log2(e)) = 2*ln2

typedef __attribute__((ext_vector_type(8))) short bf16x8;
typedef __attribute__((ext_vector_type(4))) float f32x4;

#if __has_builtin(__builtin_amdgcn_exp2f)
#define EXP2(x) __builtin_amdgcn_exp2f(x)
#else
#define EXP2(x) __expf((x) * 0.69314718f)
#endif

static __device__ __forceinline__ unsigned short f2bf(float x) {
  unsigned int u = __float_as_uint(x);
  unsigned int r = (u + 0x7FFFu + ((u >> 16) & 1u)) >> 16;
  return (unsigned short)r;
}

// ---------------------------------------------------------------- normalize
__global__ __launch_bounds__(256) void normalize_kernel(
    const float* __restrict__ emb_i, const float* __restrict__ emb_j,
    unsigned short* __restrict__ zb) {
  int w = threadIdx.x >> 6, lane = threadIdx.x & 63;
  int row = blockIdx.x * 4 + w;
  const float* src = (row < NHALF) ? (emb_i + (size_t)row * DIM)
                                   : (emb_j + (size_t)(row - NHALF) * DIM);
  float4 v = ((const float4*)src)[lane];
  float ss = v.x * v.x + v.y * v.y + v.z * v.z + v.w * v.w;
  #pragma unroll
  for (int off = 32; off; off >>= 1) ss += __shfl_down(ss, off, 64);
  float total = __shfl(ss, 0, 64);
  float inv = SCALE / fmaxf(sqrtf(total), 1e-12f);
  ushort4 o;
  o.x = f2bf(v.x * inv); o.y = f2bf(v.y * inv);
  o.z = f2bf(v.z * inv); o.w = f2bf(v.w * inv);
  ((ushort4*)&zb[(size_t)row * DIM])[lane] = o;
}

// ------------- LDS-free MFMA tile + exp2 + atomic sums + fused final reduce
__global__ __launch_bounds__(256) void denom_kernel(
    const unsigned short* __restrict__ zb, float* __restrict__ dsum,
    float* __restrict__ posSum, int* __restrict__ cnt,
    float* __restrict__ out) {
  __shared__ float red[512];
  __shared__ int tick;

  // decode triangle tile id -> (bx, by), bx <= by
  int t = blockIdx.x;
  int by = (int)((sqrtf(8.0f * (float)t + 1.0f) - 1.0f) * 0.5f);
  while ((by + 1) * (by + 2) / 2 <= t) ++by;
  while (by * (by + 1) / 2 > t) --by;
  int bx = t - by * (by + 1) / 2;

  const int tid = threadIdx.x;
  const int w = tid >> 6;
  const int lane = tid & 63;
  const int wr = w >> 1, wc = w & 1;  // 2x2 wave grid, 64x64 each
  const int quad = lane >> 4;
  const int m16 = lane & 15;
  const int row0 = bx * BM;
  const int col0 = by * BM;

  // Per-lane fragment base pointers (A-operand layout: lane m=m16 holds
  // k = quad*8..quad*8+7 of its row; rows i*16 apart).
  const unsigned short* aBase =
      zb + (size_t)(row0 + wr * 64 + m16) * DIM + quad * 8;
  const unsigned short* bBase =
      zb + (size_t)(col0 + wc * 64 + m16) * DIM + quad * 8;

  f32x4 acc[4][4];
  #pragma unroll
  for (int i = 0; i < 4; ++i)
    #pragma unroll
    for (int j = 0; j < 4; ++j) {
      f32x4 z4 = {0.f, 0.f, 0.f, 0.f};
      acc[i][j] = z4;
    }

  // 8 k-steps of 32; all loads independent, no barriers anywhere.
  #pragma unroll 2
  for (int ks = 0; ks < 8; ++ks) {
    bf16x8 af[4], bfr[4];
    #pragma unroll
    for (int i = 0; i < 4; ++i)
      af[i] = *(const bf16x8*)(aBase + (size_t)i * 16 * DIM + ks * 32);
    #pragma unroll
    for (int j = 0; j < 4; ++j)
      bfr[j] = *(const bf16x8*)(bBase + (size_t)j * 16 * DIM + ks * 32);
    #pragma unroll
    for (int i = 0; i < 4; ++i)
      #pragma unroll
      for (int j = 0; j < 4; ++j)
        acc[i][j] = __builtin_amdgcn_mfma_f32_16x16x32_bf16(
            af[i], bfr[j], acc[i][j], 0, 0, 0);
  }

  // pos tiles: col0 - row0 == NHALF; global pair element <=> local col==row.
  if (col0 - row0 == NHALF) {
    float p = 0.f;
    if (wr == wc) {
      int r = m16 - quad * 4;
      if (r >= 0 && r < 4) {
        #pragma unroll
        for (int i = 0; i < 4; ++i) p += acc[i][i][r];
      }
    }
    #pragma unroll
    for (int off = 32; off; off >>= 1) p += __shfl_down(p, off, 64);
    if (lane == 0 && p != 0.f) atomicAdd(posSum, p);
    if (lane == 0 && p == 0.f && wr == wc) atomicAdd(posSum, p);  // keep exact
  }

  // Epilogue. C layout: local col = wc*64+j*16+m16, row = wr*64+i*16+quad*4+r.
  if (bx != by) {
    float rs[4][4];
    float cs[4] = {0.f, 0.f, 0.f, 0.f};
    #pragma unroll
    for (int i = 0; i < 4; ++i)
      #pragma unroll
      for (int r = 0; r < 4; ++r) rs[i][r] = 0.f;
    #pragma unroll
    for (int i = 0; i < 4; ++i)
      #pragma unroll
      for (int j = 0; j < 4; ++j)
        #pragma unroll
        for (int r = 0; r < 4; ++r) {
          float e = EXP2(acc[i][j][r]);
          rs[i][r] += e;
          cs[j] += e;
        }
    #pragma unroll
    for (int i = 0; i < 4; ++i)
      #pragma unroll
      for (int r = 0; r < 4; ++r) {
        float v = rs[i][r];
        v += __shfl_xor(v, 1, 16);
        v += __shfl_xor(v, 2, 16);
        v += __shfl_xor(v, 4, 16);
        v += __shfl_xor(v, 8, 16);
        if (m16 == 0) red[wc * 128 + wr * 64 + i * 16 + quad * 4 + r] = v;
      }
    #pragma unroll
    for (int j = 0; j < 4; ++j) {
      float v = cs[j];
      v += __shfl_xor(v, 16, 64);
      v += __shfl_xor(v, 32, 64);
      if (quad == 0) red[256 + wr * 128 + wc * 64 + j * 16 + m16] = v;
    }
    __syncthreads();
    if (tid < 128) {
      atomicAdd(&dsum[row0 + tid], red[tid] + red[128 + tid]);
    } else {
      int c = tid - 128;
      atomicAdd(&dsum[col0 + c], red[256 + c] + red[384 + c]);
    }
  } else {
    float rs[4][4];
    #pragma unroll
    for (int i = 0; i < 4; ++i)
      #pragma unroll
      for (int r = 0; r < 4; ++r) rs[i][r] = 0.f;
    #pragma unroll
    for (int i = 0; i < 4; ++i)
      #pragma unroll
      for (int j = 0; j < 4; ++j) {
        int lcol = wc * 64 + j * 16 + m16;
        #pragma unroll
        for (int r = 0; r < 4; ++r) {
          int lrow = wr * 64 + i * 16 + quad * 4 + r;
          float e = (lrow == lcol) ? 0.f : EXP2(acc[i][j][r]);
          rs[i][r] += e;
        }
      }
    #pragma unroll
    for (int i = 0; i < 4; ++i)
      #pragma unroll
      for (int r = 0; r < 4; ++r) {
        float v = rs[i][r];
        v += __shfl_xor(v, 1, 16);
        v += __shfl_xor(v, 2, 16);
        v += __shfl_xor(v, 4, 16);
        v += __shfl_xor(v, 8, 16);
        if (m16 == 0) red[wc * 128 + wr * 64 + i * 16 + quad * 4 + r] = v;
      }
    __syncthreads();
    if (tid < 128) atomicAdd(&dsum[row0 + tid], red[tid] + red[128 + tid]);
  }

  // ---- fence-free fused finish (ticket after barrier: all atomics drained)
  __syncthreads();
  if (tid == 0)
    tick = __hip_atomic_fetch_add(cnt, 1, __ATOMIC_RELAXED,
                                  __HIP_MEMORY_SCOPE_AGENT);
  __syncthreads();
  int td = tick;
  if (td < NTRI - NRED) return;
  int slice = td - (NTRI - NRED);

  if (tid == 0) {
    while (__hip_atomic_load(cnt, __ATOMIC_ACQUIRE,
                             __HIP_MEMORY_SCOPE_AGENT) < NTRI)
      __builtin_amdgcn_s_sleep(8);
  }
  __syncthreads();

  int r = slice * 256 + tid;
  float s = __hip_atomic_load(&dsum[r], __ATOMIC_RELAXED,
                              __HIP_MEMORY_SCOPE_AGENT);
  float v = -logf(s);
  #pragma unroll
  for (int off = 32; off; off >>= 1) v += __shfl_down(v, off, 64);
  if (lane == 0) red[w] = v;
  __syncthreads();
  if (tid == 0) {
    float total = red[0] + red[1] + red[2] + red[3];
    if (slice == 0) {
      float ps = __hip_atomic_load(posSum, __ATOMIC_RELAXED,
                                   __HIP_MEMORY_SCOPE_AGENT);
      total += POSMUL * ps;
    }
    atomicAdd(out, total * (1.0f / 8192.0f));
  }
}

extern "C" void kernel_launch(void* const* d_in, const int* in_sizes, int n_in,
                              void* d_out, int out_size, void* d_ws,
                              size_t ws_size, hipStream_t stream) {
  const float* emb_i = (const float*)d_in[0];
  const float* emb_j = (const float*)d_in[1];
  unsigned short* zb = (unsigned short*)d_ws;         // 4 MB
  float* dsum = (float*)(zb + (size_t)NROWS * DIM);   // 8192 f32
  float* posSum = dsum + NROWS;                       // 1 f32
  int* cnt = (int*)(posSum + 1);                      // 1 int
  float* out = (float*)d_out;

  hipMemsetAsync(dsum, 0, NROWS * sizeof(float) + sizeof(float) + sizeof(int),
                 stream);
  hipMemsetAsync(out, 0, sizeof(float), stream);
  normalize_kernel<<<NROWS / 4, 256, 0, stream>>>(emb_i, emb_j, zb);
  denom_kernel<<<NTRI, 256, 0, stream>>>(zb, dsum, posSum, cnt, out);
}